// Round 1
// baseline (4918.135 us; speedup 1.0000x reference)
//
#include <hip/hip_runtime.h>
#include <hip/hip_bf16.h>
#include <math.h>

constexpr int Dm = 1024;
constexpr int Hh = 16;
constexpr int DHd = 64;
constexpr int Ff = 4096;
constexpr int Ss = 512;
constexpr int Bbatch = 16;
constexpr int NT = Bbatch * Ss;   // 8192 tokens
constexpr float EPSc = 1e-5f;

static __device__ __forceinline__ float gelu_f(float v) {
    return 0.5f * v * (1.0f + erff(v * 0.70710678118654752f));
}

// ---------------- LayerNorm: one block (256 thr) per row, 4 elems/thread ----
__global__ void __launch_bounds__(256) ln_kernel(const float* __restrict__ x,
                                                 const float* __restrict__ gamma,
                                                 const float* __restrict__ beta,
                                                 float* __restrict__ out) {
    const int row = blockIdx.x;
    const int tid = threadIdx.x;
    const int lane = tid & 63, w = tid >> 6;
    const float4* xr = reinterpret_cast<const float4*>(x + (size_t)row * Dm);
    float4 xv = xr[tid];
    float s  = xv.x + xv.y + xv.z + xv.w;
    float ss = xv.x * xv.x + xv.y * xv.y + xv.z * xv.z + xv.w * xv.w;
    #pragma unroll
    for (int o = 32; o > 0; o >>= 1) {
        s  += __shfl_down(s,  o, 64);
        ss += __shfl_down(ss, o, 64);
    }
    __shared__ float red[2][4];
    if (lane == 0) { red[0][w] = s; red[1][w] = ss; }
    __syncthreads();
    float st  = red[0][0] + red[0][1] + red[0][2] + red[0][3];
    float sst = red[1][0] + red[1][1] + red[1][2] + red[1][3];
    float mean = st * (1.0f / Dm);
    float var  = sst * (1.0f / Dm) - mean * mean;
    float inv  = rsqrtf(var + EPSc);
    float4 g = reinterpret_cast<const float4*>(gamma)[tid];
    float4 b = reinterpret_cast<const float4*>(beta)[tid];
    float4 o4;
    o4.x = (xv.x - mean) * inv * g.x + b.x;
    o4.y = (xv.y - mean) * inv * g.y + b.y;
    o4.z = (xv.z - mean) * inv * g.z + b.z;
    o4.w = (xv.w - mean) * inv * g.w + b.w;
    reinterpret_cast<float4*>(out + (size_t)row * Dm)[tid] = o4;
}

// ---------------- Tiled fp32 GEMM: 64x64 tile, BK=16, 256 thr, 4x4/thread ---
// BMODE 0: B[k][j] = Bm[k*ldb + n0 + j]        (row-major slice)
// BMODE 1: B[k][j] = Bm[((n0>>6)*K + k)*64+j]  (per-head [H,D,DH] weights)
// CMODE 0: C = v (+bias)   CMODE 1: C = v + bias + res   CMODE 2: C += v (+bias)
// ACT 1: exact GELU applied after bias.
template<int BMODE, int ACT, int CMODE>
__global__ void __launch_bounds__(256) gemm64(const float* __restrict__ A, int lda,
                                              const float* __restrict__ Bm, int ldb,
                                              const float* __restrict__ bias,
                                              const float* __restrict__ res,
                                              float* __restrict__ C, int ldc,
                                              int M, int K) {
    __shared__ float As[16][68];   // [k][m], +4 pad keeps float4 rows 16B-aligned
    __shared__ float Bs[16][68];   // [k][n]
    const int tid = threadIdx.x;
    const int tx = tid & 15, ty = tid >> 4;
    const int n0 = blockIdx.x * 64, m0 = blockIdx.y * 64;
    const int arow = tid >> 2, akq = (tid & 3) * 4;
    const int bcol = tid & 63, bkr = (tid >> 6) * 4;
    float acc[4][4] = {};
    for (int k0 = 0; k0 < K; k0 += 16) {
        float4 av = *reinterpret_cast<const float4*>(
            A + (size_t)(m0 + arow) * lda + k0 + akq);
        As[akq + 0][arow] = av.x;
        As[akq + 1][arow] = av.y;
        As[akq + 2][arow] = av.z;
        As[akq + 3][arow] = av.w;
        #pragma unroll
        for (int i = 0; i < 4; i++) {
            int k = bkr + i;
            float bv;
            if (BMODE == 0) bv = Bm[(size_t)(k0 + k) * ldb + n0 + bcol];
            else            bv = Bm[((size_t)(n0 >> 6) * K + k0 + k) * 64 + bcol];
            Bs[k][bcol] = bv;
        }
        __syncthreads();
        #pragma unroll
        for (int kk = 0; kk < 16; kk++) {
            float4 a = *reinterpret_cast<const float4*>(&As[kk][ty * 4]);
            float4 b = *reinterpret_cast<const float4*>(&Bs[kk][tx * 4]);
            acc[0][0] += a.x * b.x; acc[0][1] += a.x * b.y;
            acc[0][2] += a.x * b.z; acc[0][3] += a.x * b.w;
            acc[1][0] += a.y * b.x; acc[1][1] += a.y * b.y;
            acc[1][2] += a.y * b.z; acc[1][3] += a.y * b.w;
            acc[2][0] += a.z * b.x; acc[2][1] += a.z * b.y;
            acc[2][2] += a.z * b.z; acc[2][3] += a.z * b.w;
            acc[3][0] += a.w * b.x; acc[3][1] += a.w * b.y;
            acc[3][2] += a.w * b.z; acc[3][3] += a.w * b.w;
        }
        __syncthreads();
    }
    #pragma unroll
    for (int i = 0; i < 4; i++) {
        int r = m0 + ty * 4 + i;
        #pragma unroll
        for (int j = 0; j < 4; j++) {
            int c = n0 + tx * 4 + j;
            float v = acc[i][j];
            if (bias != nullptr) v += bias[c];
            if (ACT == 1) v = gelu_f(v);
            size_t off = (size_t)r * ldc + c;
            if (CMODE == 1) v += res[off];
            if (CMODE == 2) C[off] += v;
            else            C[off] = v;
        }
    }
}

// ---------------- Causal attention: one wave per (b,h,q) row ----------------
// Q/K/V layout: [B*S, H*DH] (token-major, heads concatenated)
__global__ void __launch_bounds__(256) attn_kernel(const float* __restrict__ Q,
                                                   const float* __restrict__ K,
                                                   const float* __restrict__ V,
                                                   float* __restrict__ O) {
    const int tid = threadIdx.x;
    const int lane = tid & 63, w = tid >> 6;
    const int gw = blockIdx.x * 4 + w;          // row id over B*H*S
    const int q = gw & (Ss - 1);
    const int h = (gw >> 9) & (Hh - 1);
    const int b = gw >> 13;
    const int nt = q + 1;                       // causal: t <= q

    __shared__ float qs[4][64];
    const size_t headoff = (size_t)h * DHd;
    const float* qptr = Q + ((size_t)(b * Ss + q) * Dm + headoff);
    qs[w][lane] = qptr[lane];                   // same wave produces+consumes

    float p[8];
    float mx = -1e30f;
    const float* Kb = K + ((size_t)(b * Ss) * Dm + headoff);
    #pragma unroll
    for (int c = 0; c < 8; c++) {
        int t = c * 64 + lane;
        float sc = -1e30f;
        if (t < nt) {
            const float4* kr = reinterpret_cast<const float4*>(Kb + (size_t)t * Dm);
            const float4* qr = reinterpret_cast<const float4*>(qs[w]);
            float a = 0.f;
            #pragma unroll
            for (int d = 0; d < 16; d++) {
                float4 kv = kr[d], qv = qr[d];
                a += kv.x * qv.x + kv.y * qv.y + kv.z * qv.z + kv.w * qv.w;
            }
            sc = a * 0.125f;                    // 1/sqrt(64)
        }
        p[c] = sc;
        mx = fmaxf(mx, sc);
    }
    #pragma unroll
    for (int o = 1; o < 64; o <<= 1) mx = fmaxf(mx, __shfl_xor(mx, o, 64));
    float sum = 0.f;
    #pragma unroll
    for (int c = 0; c < 8; c++) {
        int t = c * 64 + lane;
        float e = (t < nt) ? __expf(p[c] - mx) : 0.f;
        p[c] = e;
        sum += e;
    }
    #pragma unroll
    for (int o = 1; o < 64; o <<= 1) sum += __shfl_xor(sum, o, 64);
    const float inv = 1.0f / sum;

    float acc = 0.f;
    const float* Vb = V + ((size_t)(b * Ss) * Dm + headoff);
    #pragma unroll
    for (int c = 0; c < 8; c++) {
        int base = c * 64;
        if (base < nt) {
            int cnt = min(64, nt - base);
            for (int l = 0; l < cnt; l++) {
                float pb = __shfl(p[c], l, 64);
                acc += pb * Vb[(size_t)(base + l) * Dm + lane];
            }
        }
    }
    O[(size_t)(b * Ss + q) * Dm + headoff + lane] = acc * inv;
}

extern "C" void kernel_launch(void* const* d_in, const int* in_sizes, int n_in,
                              void* d_out, int out_size, void* d_ws, size_t ws_size,
                              hipStream_t stream) {
    const float* x   = (const float*)d_in[0];
    const float* Wq  = (const float*)d_in[1];
    const float* Wk  = (const float*)d_in[2];
    const float* Wv  = (const float*)d_in[3];
    const float* Wo  = (const float*)d_in[4];
    const float* bo  = (const float*)d_in[5];
    const float* g1  = (const float*)d_in[6];
    const float* be1 = (const float*)d_in[7];
    const float* g2  = (const float*)d_in[8];
    const float* be2 = (const float*)d_in[9];
    const float* W1  = (const float*)d_in[10];
    const float* b1  = (const float*)d_in[11];
    const float* W2  = (const float*)d_in[12];
    const float* b2  = (const float*)d_in[13];
    float* out = (float*)d_out;

    // workspace layout (fp32): 4 x [NT, Dm] buffers = 134 MB, aliased reuse
    float* ws = (float*)d_ws;
    float* n1 = ws;                          // LN1 out; later reused as concat
    float* Qb = ws + (size_t)NT * Dm;        // later reused as n2
    float* Kb = Qb + (size_t)NT * Dm;        // later reused as h1 chunk
    float* Vb = Kb + (size_t)NT * Dm;
    float* cc = n1;
    float* n2 = Qb;
    float* h1 = Kb;

    dim3 gg(Dm / 64, NT / 64);               // (16, 128)

    ln_kernel<<<NT, 256, 0, stream>>>(x, g1, be1, n1);
    gemm64<1, 0, 0><<<gg, 256, 0, stream>>>(n1, Dm, Wq, 0, nullptr, nullptr, Qb, Dm, NT, Dm);
    gemm64<1, 0, 0><<<gg, 256, 0, stream>>>(n1, Dm, Wk, 0, nullptr, nullptr, Kb, Dm, NT, Dm);
    gemm64<1, 0, 0><<<gg, 256, 0, stream>>>(n1, Dm, Wv, 0, nullptr, nullptr, Vb, Dm, NT, Dm);
    attn_kernel<<<NT * Hh / 4, 256, 0, stream>>>(Qb, Kb, Vb, cc);
    gemm64<0, 0, 1><<<gg, 256, 0, stream>>>(cc, Dm, Wo, Dm, bo, x, out, Dm, NT, Dm);
    ln_kernel<<<NT, 256, 0, stream>>>(out, g2, be2, n2);
    for (int c = 0; c < 4; c++) {
        int f0 = c * 1024;
        gemm64<0, 1, 0><<<gg, 256, 0, stream>>>(n2, Dm, W1 + f0, Ff, b1 + f0,
                                                nullptr, h1, Dm, NT, Dm);
        gemm64<0, 0, 2><<<gg, 256, 0, stream>>>(h1, Dm, W2 + (size_t)f0 * Dm, Dm,
                                                (c == 0) ? b2 : nullptr, nullptr,
                                                out, Dm, NT, Dm);
    }
}

// Round 2
// 473.368 us; speedup vs baseline: 10.3897x; 10.3897x over previous
//
#include <hip/hip_runtime.h>
#include <hip/hip_bf16.h>
#include <math.h>

constexpr int Dm = 1024;
constexpr int Hh = 16;
constexpr int Ff = 4096;
constexpr int Ss = 512;
constexpr int Bbatch = 16;
constexpr int NT = Bbatch * Ss;   // 8192 tokens
constexpr float EPSc = 1e-5f;

typedef __attribute__((ext_vector_type(8))) short bfrag;   // 8 bf16 (4 VGPR)
typedef __attribute__((ext_vector_type(4))) float f32x4;

static __device__ __forceinline__ float gelu_f(float v) {
    return 0.5f * v * (1.0f + erff(v * 0.70710678118654752f));
}

static __device__ __forceinline__ void gload16(const void* g, void* l) {
    __builtin_amdgcn_global_load_lds((__attribute__((address_space(1))) void*)g,
                                     (__attribute__((address_space(3))) void*)l,
                                     16, 0, 0);
}

// XOR swizzle for [rows][128B-row] LDS tiles (G4): byte ^= ((row&7)<<4)
#define SWZ(row, colb) ((row) * 128 + ((colb) ^ (((row) & 7) << 4)))

// ---------------- transpose + fp32->bf16 convert: in [R][C] -> out [C][R] ---
__global__ void __launch_bounds__(256) transpose_cvt(const float* __restrict__ in,
                                                     __hip_bfloat16* __restrict__ out,
                                                     int R, int C,
                                                     long in_zs, long out_zs) {
    __shared__ float tile[32][33];
    const float* inz = in + (size_t)blockIdx.z * in_zs;
    __hip_bfloat16* outz = out + (size_t)blockIdx.z * out_zs;
    const int c0 = blockIdx.x * 32, r0 = blockIdx.y * 32;
    const int tx = threadIdx.x & 31, ty4 = (threadIdx.x >> 5) * 4;
    #pragma unroll
    for (int i = 0; i < 4; i++)
        tile[ty4 + i][tx] = inz[(size_t)(r0 + ty4 + i) * C + c0 + tx];
    __syncthreads();
    #pragma unroll
    for (int i = 0; i < 4; i++)
        outz[(size_t)(c0 + ty4 + i) * R + r0 + tx] = __float2bfloat16(tile[tx][ty4 + i]);
}

// ---------------- LayerNorm fp32 in -> bf16 out ----------------------------
__global__ void __launch_bounds__(256) ln_bf16(const float* __restrict__ x,
                                               const float* __restrict__ gamma,
                                               const float* __restrict__ beta,
                                               __hip_bfloat16* __restrict__ out) {
    const int row = blockIdx.x;
    const int tid = threadIdx.x;
    const int lane = tid & 63, w = tid >> 6;
    float4 xv = reinterpret_cast<const float4*>(x + (size_t)row * Dm)[tid];
    float s  = xv.x + xv.y + xv.z + xv.w;
    float ss = xv.x * xv.x + xv.y * xv.y + xv.z * xv.z + xv.w * xv.w;
    #pragma unroll
    for (int o = 32; o > 0; o >>= 1) {
        s  += __shfl_down(s,  o, 64);
        ss += __shfl_down(ss, o, 64);
    }
    __shared__ float red[2][4];
    if (lane == 0) { red[0][w] = s; red[1][w] = ss; }
    __syncthreads();
    float st  = red[0][0] + red[0][1] + red[0][2] + red[0][3];
    float sst = red[1][0] + red[1][1] + red[1][2] + red[1][3];
    float mean = st * (1.0f / Dm);
    float var  = sst * (1.0f / Dm) - mean * mean;
    float inv  = rsqrtf(var + EPSc);
    float4 g = reinterpret_cast<const float4*>(gamma)[tid];
    float4 b = reinterpret_cast<const float4*>(beta)[tid];
    __hip_bfloat16 t[4] __attribute__((aligned(8)));
    t[0] = __float2bfloat16((xv.x - mean) * inv * g.x + b.x);
    t[1] = __float2bfloat16((xv.y - mean) * inv * g.y + b.y);
    t[2] = __float2bfloat16((xv.z - mean) * inv * g.z + b.z);
    t[3] = __float2bfloat16((xv.w - mean) * inv * g.w + b.w);
    *reinterpret_cast<ushort4*>(out + (size_t)row * Dm + tid * 4) =
        *reinterpret_cast<ushort4*>(t);
}

// ---------------- bf16 MFMA GEMM (m97 structure): C = A[M,K] x Bt[N,K]^T ----
// 128x128 tile, BK=32, 256 thr (4 waves 2x2), global_load_lds staging.
// EPI 0: bf16 C                EPI 1: f32 C = acc + bias + res
// EPI 2: bf16 C = gelu(acc+b)  EPI 3: f32 C += acc + bias
template<int EPI>
__global__ void __launch_bounds__(256) gemm_mfma(const __hip_bfloat16* __restrict__ A, int lda,
                                                 const __hip_bfloat16* __restrict__ Bt, int ldb,
                                                 const float* __restrict__ bias,
                                                 const float* __restrict__ res,
                                                 void* __restrict__ Cout, int ldc,
                                                 int nbx, int K) {
    __shared__ __hip_bfloat16 As[128 * 32];
    __shared__ __hip_bfloat16 Bs[128 * 32];
    const int tid = threadIdx.x, l = tid & 63, w = tid >> 6;
    const int lr = l & 15, lg = l >> 4;
    // XCD-aware swizzle (nwg % 8 == 0 for all our grids)
    const int nwg = gridDim.x, cpx = nwg >> 3;
    const int bid = blockIdx.x;
    const int sbid = (bid & 7) * cpx + (bid >> 3);
    const int bx = sbid % nbx, by = sbid / nbx;
    const int m0 = by * 128, n0 = bx * 128;
    const int wr = w >> 1, wc = w & 1;
    const int sr = l >> 2, scc = (l & 3) * 8;   // staging row-in-slot, col

    f32x4 acc[4][4] = {};
    for (int k0 = 0; k0 < K; k0 += 32) {
        #pragma unroll
        for (int j = 0; j < 2; j++) {
            const int slot = w * 2 + j;
            const int r = slot * 16 + sr;
            gload16(A  + (size_t)(m0 + r) * lda + k0 + scc, As + slot * 512);
            gload16(Bt + (size_t)(n0 + r) * ldb + k0 + scc, Bs + slot * 512);
        }
        __syncthreads();
        bfrag a[4], b[4];
        #pragma unroll
        for (int mi = 0; mi < 4; mi++)
            a[mi] = *reinterpret_cast<const bfrag*>(As + (wr * 64 + mi * 16 + lr) * 32 + lg * 8);
        #pragma unroll
        for (int ni = 0; ni < 4; ni++)
            b[ni] = *reinterpret_cast<const bfrag*>(Bs + (wc * 64 + ni * 16 + lr) * 32 + lg * 8);
        #pragma unroll
        for (int mi = 0; mi < 4; mi++)
            #pragma unroll
            for (int ni = 0; ni < 4; ni++)
                acc[mi][ni] = __builtin_amdgcn_mfma_f32_16x16x32_bf16(a[mi], b[ni], acc[mi][ni], 0, 0, 0);
        __syncthreads();
    }
    const int rb = m0 + wr * 64 + lg * 4;
    const int cb = n0 + wc * 64 + lr;
    #pragma unroll
    for (int mi = 0; mi < 4; mi++) {
        #pragma unroll
        for (int ni = 0; ni < 4; ni++) {
            #pragma unroll
            for (int rg = 0; rg < 4; rg++) {
                const int row = rb + mi * 16 + rg;
                const int col = cb + ni * 16;
                const size_t off = (size_t)row * ldc + col;
                const float v = acc[mi][ni][rg];
                if (EPI == 0) {
                    ((__hip_bfloat16*)Cout)[off] = __float2bfloat16(v);
                } else if (EPI == 1) {
                    ((float*)Cout)[off] = v + bias[col] + res[off];
                } else if (EPI == 2) {
                    ((__hip_bfloat16*)Cout)[off] = __float2bfloat16(gelu_f(v + bias[col]));
                } else {
                    ((float*)Cout)[off] = ((float*)Cout)[off] + v + bias[col];
                }
            }
        }
    }
}

// ---------------- Flash attention, bf16 MFMA -------------------------------
// QKV [NT][3072]: Q at col 0, K at 1024, V at 2048 (+h*64). Block = (b,h,qt):
// 64 Q-rows, 4 waves x 16 rows. K/V tiles of 64 keys, online softmax.
__global__ void __launch_bounds__(256) attn_mfma(const __hip_bfloat16* __restrict__ QKV,
                                                 __hip_bfloat16* __restrict__ Oc) {
    constexpr int LDQ = 3072;
    __shared__ __hip_bfloat16 Qs[64 * 64];
    __shared__ __hip_bfloat16 Ks[64 * 64];
    __shared__ __hip_bfloat16 Vts[64 * 64];   // V^T [feat][key]
    __shared__ __hip_bfloat16 Ps[4][16 * 64]; // per-wave P
    const int tid = threadIdx.x, l = tid & 63, w = tid >> 6;
    const int lr = l & 15, lg = l >> 4;
    const int qt = blockIdx.x & 7;
    const int h  = (blockIdx.x >> 3) & 15;
    const int b  = blockIdx.x >> 7;

    const __hip_bfloat16* Qg = QKV + (size_t)(b * Ss + qt * 64) * LDQ + h * 64;
    const __hip_bfloat16* Kg = QKV + (size_t)(b * Ss) * LDQ + 1024 + h * 64;
    const __hip_bfloat16* Vg = QKV + (size_t)(b * Ss) * LDQ + 2048 + h * 64;

    const int r8 = l >> 3;                    // row-in-slot 0..7
    const int scol = 8 * ((l & 7) ^ r8);      // pre-swizzled source col (elems)

    #pragma unroll
    for (int j = 0; j < 2; j++) {
        const int slot = w * 2 + j;
        gload16(Qg + (size_t)(slot * 8 + r8) * LDQ + scol, Qs + slot * 512);
    }

    float m_run[4] = {-1e30f, -1e30f, -1e30f, -1e30f};
    float l_run[4] = {0.f, 0.f, 0.f, 0.f};
    f32x4 acc_o[4] = {};

    for (int kt = 0; kt <= qt; ++kt) {
        __syncthreads();   // prev-iter LDS reads done (iter 0: Q staged)
        #pragma unroll
        for (int j = 0; j < 2; j++) {
            const int slot = w * 2 + j;
            gload16(Kg + (size_t)(kt * 64 + slot * 8 + r8) * LDQ + scol, Ks + slot * 512);
        }
        // V^T: reg-stage with swizzled transpose writes
        unsigned short* vt = reinterpret_cast<unsigned short*>(Vts);
        #pragma unroll
        for (int j = 0; j < 2; j++) {
            const int e = tid + j * 256;
            const int key = e >> 3, f0 = (e & 7) * 8;
            const uint4 raw = *reinterpret_cast<const uint4*>(
                Vg + (size_t)(kt * 64 + key) * LDQ + f0);
            const unsigned int rw[4] = {raw.x, raw.y, raw.z, raw.w};
            #pragma unroll
            for (int e2 = 0; e2 < 8; e2++) {
                const int feat = f0 + e2;
                const int ad = feat * 128 + ((key * 2) ^ ((feat & 7) << 4));
                vt[ad >> 1] = (unsigned short)(rw[e2 >> 1] >> ((e2 & 1) * 16));
            }
        }
        __syncthreads();   // K, V^T staged

        // QK^T -> S [16 q-rows][64 keys] per wave
        f32x4 s4[4] = {};
        #pragma unroll
        for (int kk = 0; kk < 2; kk++) {
            const bfrag aq = *reinterpret_cast<const bfrag*>(
                (const char*)Qs + SWZ(w * 16 + lr, kk * 64 + lg * 16));
            #pragma unroll
            for (int ni = 0; ni < 4; ni++) {
                const bfrag bk = *reinterpret_cast<const bfrag*>(
                    (const char*)Ks + SWZ(ni * 16 + lr, kk * 64 + lg * 16));
                s4[ni] = __builtin_amdgcn_mfma_f32_16x16x32_bf16(aq, bk, s4[ni], 0, 0, 0);
            }
        }
        float p[4][4];
        #pragma unroll
        for (int ni = 0; ni < 4; ni++)
            #pragma unroll
            for (int rg = 0; rg < 4; rg++)
                p[ni][rg] = s4[ni][rg] * 0.125f;
        if (kt == qt) {   // causal mask on diagonal tile
            #pragma unroll
            for (int ni = 0; ni < 4; ni++)
                #pragma unroll
                for (int rg = 0; rg < 4; rg++)
                    if (ni * 16 + lr > w * 16 + lg * 4 + rg) p[ni][rg] = -1e30f;
        }
        float sf[4];
        #pragma unroll
        for (int rg = 0; rg < 4; rg++) {
            float mx = fmaxf(fmaxf(p[0][rg], p[1][rg]), fmaxf(p[2][rg], p[3][rg]));
            #pragma unroll
            for (int o = 1; o < 16; o <<= 1) mx = fmaxf(mx, __shfl_xor(mx, o, 64));
            const float mn = fmaxf(m_run[rg], mx);
            sf[rg] = __expf(m_run[rg] - mn);
            m_run[rg] = mn;
        }
        float rsum[4] = {};
        #pragma unroll
        for (int ni = 0; ni < 4; ni++)
            #pragma unroll
            for (int rg = 0; rg < 4; rg++) {
                const float e = __expf(p[ni][rg] - m_run[rg]);
                p[ni][rg] = e;
                rsum[rg] += e;
            }
        #pragma unroll
        for (int rg = 0; rg < 4; rg++) {
            #pragma unroll
            for (int o = 1; o < 16; o <<= 1) rsum[rg] += __shfl_xor(rsum[rg], o, 64);
            l_run[rg] = l_run[rg] * sf[rg] + rsum[rg];
        }
        #pragma unroll
        for (int di = 0; di < 4; di++)
            #pragma unroll
            for (int rg = 0; rg < 4; rg++)
                acc_o[di][rg] *= sf[rg];
        // P -> bf16 -> per-wave LDS (swizzled), then PV
        unsigned short* pw = reinterpret_cast<unsigned short*>(Ps[w]);
        #pragma unroll
        for (int ni = 0; ni < 4; ni++)
            #pragma unroll
            for (int rg = 0; rg < 4; rg++) {
                const int prow = lg * 4 + rg;
                const int ad = SWZ(prow, (ni * 16 + lr) * 2);
                __hip_bfloat16 pb = __float2bfloat16(p[ni][rg]);
                pw[ad >> 1] = *reinterpret_cast<unsigned short*>(&pb);
            }
        #pragma unroll
        for (int kk = 0; kk < 2; kk++) {
            const bfrag pa = *reinterpret_cast<const bfrag*>(
                (const char*)Ps[w] + SWZ(lr, kk * 64 + lg * 16));
            #pragma unroll
            for (int di = 0; di < 4; di++) {
                const bfrag vb = *reinterpret_cast<const bfrag*>(
                    (const char*)Vts + SWZ(di * 16 + lr, kk * 64 + lg * 16));
                acc_o[di] = __builtin_amdgcn_mfma_f32_16x16x32_bf16(pa, vb, acc_o[di], 0, 0, 0);
            }
        }
    }
    #pragma unroll
    for (int di = 0; di < 4; di++)
        #pragma unroll
        for (int rg = 0; rg < 4; rg++) {
            const int q = qt * 64 + w * 16 + lg * 4 + rg;
            const float v = acc_o[di][rg] / l_run[rg];
            Oc[(size_t)(b * Ss + q) * Dm + h * 64 + di * 16 + lr] = __float2bfloat16(v);
        }
}

extern "C" void kernel_launch(void* const* d_in, const int* in_sizes, int n_in,
                              void* d_out, int out_size, void* d_ws, size_t ws_size,
                              hipStream_t stream) {
    const float* x   = (const float*)d_in[0];
    const float* Wq  = (const float*)d_in[1];
    const float* Wk  = (const float*)d_in[2];
    const float* Wv  = (const float*)d_in[3];
    const float* Wo  = (const float*)d_in[4];
    const float* bo  = (const float*)d_in[5];
    const float* g1  = (const float*)d_in[6];
    const float* be1 = (const float*)d_in[7];
    const float* g2  = (const float*)d_in[8];
    const float* be2 = (const float*)d_in[9];
    const float* W1  = (const float*)d_in[10];
    const float* b1  = (const float*)d_in[11];
    const float* W2  = (const float*)d_in[12];
    const float* b2  = (const float*)d_in[13];
    float* out = (float*)d_out;

    // workspace (bytes): bf16 weights 24MB | n1/concat/n2 16MB | QKV 48MB, h1 64MB
    char* wsb = (char*)d_ws;
    __hip_bfloat16* WqkvT = (__hip_bfloat16*)(wsb);                 // [3072][1024]
    __hip_bfloat16* WoT   = (__hip_bfloat16*)(wsb + 6291456);       // [1024][1024]
    __hip_bfloat16* W1T   = (__hip_bfloat16*)(wsb + 8388608);       // [4096][1024]
    __hip_bfloat16* W2T   = (__hip_bfloat16*)(wsb + 16777216);      // [1024][4096]
    __hip_bfloat16* n1    = (__hip_bfloat16*)(wsb + 25165824);      // [8192][1024]
    __hip_bfloat16* QKV   = (__hip_bfloat16*)(wsb + 41943040);      // [8192][3072]
    __hip_bfloat16* concat = n1;                                    // alias (n1 dead)
    __hip_bfloat16* n2     = n1;                                    // alias (concat dead)
    __hip_bfloat16* h1     = QKV;                                   // alias (QKV dead), [8192][4096]

    // weight transpose+convert
    transpose_cvt<<<dim3(2, 32, 16), 256, 0, stream>>>(Wq, WqkvT,              1024, 64, 65536, 65536);
    transpose_cvt<<<dim3(2, 32, 16), 256, 0, stream>>>(Wk, WqkvT + 1024 * 1024, 1024, 64, 65536, 65536);
    transpose_cvt<<<dim3(2, 32, 16), 256, 0, stream>>>(Wv, WqkvT + 2048 * 1024, 1024, 64, 65536, 65536);
    transpose_cvt<<<dim3(32, 32, 1), 256, 0, stream>>>(Wo, WoT, 1024, 1024, 0, 0);
    transpose_cvt<<<dim3(128, 32, 1), 256, 0, stream>>>(W1, W1T, 1024, 4096, 0, 0);
    transpose_cvt<<<dim3(32, 128, 1), 256, 0, stream>>>(W2, W2T, 4096, 1024, 0, 0);

    ln_bf16<<<NT, 256, 0, stream>>>(x, g1, be1, n1);
    gemm_mfma<0><<<24 * 64, 256, 0, stream>>>(n1, Dm, WqkvT, Dm, nullptr, nullptr,
                                              QKV, 3072, 24, Dm);
    attn_mfma<<<NT * Hh / 64, 256, 0, stream>>>(QKV, concat);
    gemm_mfma<1><<<8 * 64, 256, 0, stream>>>(concat, Dm, WoT, Dm, bo, x,
                                             out, Dm, 8, Dm);
    ln_bf16<<<NT, 256, 0, stream>>>(out, g2, be2, n2);
    gemm_mfma<2><<<32 * 64, 256, 0, stream>>>(n2, Dm, W1T, Dm, b1, nullptr,
                                              h1, Ff, 32, Dm);
    gemm_mfma<3><<<8 * 64, 256, 0, stream>>>(h1, Ff, W2T, Ff, b2, nullptr,
                                             out, Dm, 8, Ff);
}